// Round 7
// baseline (433.313 us; speedup 1.0000x reference)
//
#include <hip/hip_runtime.h>
#include <hip/hip_bf16.h>
#include <math.h>

#define NEG_SLOPE 0.2f
#define EPS_NRM 1e-12f
#define K_IN 256
#define C_OUT 64
#define BK 32
#define ROWS_PB 128

// ---------------------------------------------------------------------------
// Kernel A: h = x @ W (+ fused a_src/a_dst scores), h stored as bf16.
// 2D register tile, x staged transposed, W staged [k][col]. (round-5/6 form)
// ---------------------------------------------------------------------------
__global__ __launch_bounds__(256) void gemm_att(
    const float* __restrict__ x, const float* __restrict__ W,
    const float* __restrict__ att_s, const float* __restrict__ att_d,
    __hip_bfloat16* __restrict__ h, float* __restrict__ a_src_arr,
    float* __restrict__ a_dst_arr, int N)
{
    __shared__ float xt[BK][ROWS_PB];   // 16 KB, transposed
    __shared__ float wt[BK][C_OUT];     // 8 KB

    int t  = threadIdx.x;
    int tx = t & 15;
    int ty = t >> 4;
    int row0 = blockIdx.x * ROWS_PB;

    int sr  = t >> 1;
    int skh = (t & 1) * 16;
    int srow = row0 + sr; if (srow >= N) srow = N - 1;
    const float* xsp = x + (size_t)srow * K_IN + skh;

    float acc[8][4];
#pragma unroll
    for (int r = 0; r < 8; ++r)
#pragma unroll
        for (int c = 0; c < 4; ++c) acc[r][c] = 0.f;

    for (int k0 = 0; k0 < K_IN; k0 += BK) {
        float4 xa = *(const float4*)(xsp + k0);
        float4 xb = *(const float4*)(xsp + k0 + 4);
        float4 xc = *(const float4*)(xsp + k0 + 8);
        float4 xd = *(const float4*)(xsp + k0 + 12);
        float4 wv4a = *(const float4*)(W + (size_t)k0 * C_OUT + t * 4);
        float4 wv4b = *(const float4*)(W + (size_t)(k0 + 16) * C_OUT + t * 4);
        __syncthreads();
        xt[skh +  0][sr] = xa.x; xt[skh +  1][sr] = xa.y;
        xt[skh +  2][sr] = xa.z; xt[skh +  3][sr] = xa.w;
        xt[skh +  4][sr] = xb.x; xt[skh +  5][sr] = xb.y;
        xt[skh +  6][sr] = xb.z; xt[skh +  7][sr] = xb.w;
        xt[skh +  8][sr] = xc.x; xt[skh +  9][sr] = xc.y;
        xt[skh + 10][sr] = xc.z; xt[skh + 11][sr] = xc.w;
        xt[skh + 12][sr] = xd.x; xt[skh + 13][sr] = xd.y;
        xt[skh + 14][sr] = xd.z; xt[skh + 15][sr] = xd.w;
        *(float4*)(&wt[ 0][0] + t * 4) = wv4a;
        *(float4*)(&wt[16][0] + t * 4) = wv4b;
        __syncthreads();

#pragma unroll
        for (int k = 0; k < BK; ++k) {
            float xv[8];
            *(float4*)&xv[0] = *(const float4*)&xt[k][ty * 8];
            *(float4*)&xv[4] = *(const float4*)&xt[k][ty * 8 + 4];
            float4 wv = *(const float4*)&wt[k][tx * 4];
#pragma unroll
            for (int r = 0; r < 8; ++r) {
                acc[r][0] += xv[r] * wv.x;
                acc[r][1] += xv[r] * wv.y;
                acc[r][2] += xv[r] * wv.z;
                acc[r][3] += xv[r] * wv.w;
            }
        }
    }

    float4 avl = *(const float4*)(att_s + tx * 4);
    float4 dvl = *(const float4*)(att_d + tx * 4);
#pragma unroll
    for (int r = 0; r < 8; ++r) {
        int row = row0 + ty * 8 + r;
        if (row >= N) continue;
        float ps = acc[r][0] * avl.x + acc[r][1] * avl.y +
                   acc[r][2] * avl.z + acc[r][3] * avl.w;
        float pd = acc[r][0] * dvl.x + acc[r][1] * dvl.y +
                   acc[r][2] * dvl.z + acc[r][3] * dvl.w;
#pragma unroll
        for (int d = 1; d < 16; d <<= 1) {
            ps += __shfl_xor(ps, d, 64);
            pd += __shfl_xor(pd, d, 64);
        }
        if (tx == 0) { a_src_arr[row] = ps; a_dst_arr[row] = pd; }
        __hip_bfloat16 hb[4];
#pragma unroll
        for (int c = 0; c < 4; ++c) hb[c] = __float2bfloat16(acc[r][c]);
        *(ushort2*)(h + (size_t)row * C_OUT + tx * 4) =
            make_ushort2(*(unsigned short*)&hb[0], *(unsigned short*)&hb[1]);
        *(ushort2*)(h + (size_t)row * C_OUT + tx * 4 + 2) =
            make_ushort2(*(unsigned short*)&hb[2], *(unsigned short*)&hb[3]);
    }
}

// ---------------------------------------------------------------------------
// CSR build over REAL edges only (self loops folded into gat_pull).
// ---------------------------------------------------------------------------
__global__ __launch_bounds__(256) void count_dst(
    const int* __restrict__ dst, int* __restrict__ cnt, int E)
{
    int i = blockIdx.x * blockDim.x + threadIdx.x;
    if (i < E) atomicAdd(&cnt[dst[i]], 1);
}

__global__ __launch_bounds__(256) void scan_p1(
    const int* __restrict__ cnt, int* __restrict__ partials, int n)
{
    int b = blockIdx.x, t = threadIdx.x;
    int base = b * 1024;
    int s = 0;
#pragma unroll
    for (int j = 0; j < 4; ++j) {
        int i = base + t * 4 + j;
        if (i < n) s += cnt[i];
    }
    for (int d = 1; d < 64; d <<= 1) s += __shfl_xor(s, d, 64);
    __shared__ int wsum[4];
    int lane = t & 63, wid = t >> 6;
    if (lane == 0) wsum[wid] = s;
    __syncthreads();
    if (t == 0) partials[b] = wsum[0] + wsum[1] + wsum[2] + wsum[3];
}

__global__ __launch_bounds__(256) void scan_p2(int* partials, int nb)
{
    __shared__ int buf[256];
    int t = threadIdx.x;
    int v = (t < nb) ? partials[t] : 0;
    buf[t] = v;
    __syncthreads();
    for (int d = 1; d < 256; d <<= 1) {
        int w = (t >= d) ? buf[t - d] : 0;
        __syncthreads();
        buf[t] += w;
        __syncthreads();
    }
    if (t < nb) partials[t] = buf[t] - v;  // exclusive
}

__global__ __launch_bounds__(256) void scan_p3(
    const int* __restrict__ cnt, const int* __restrict__ partials,
    int* __restrict__ offsets, int n)
{
    int b = blockIdx.x, t = threadIdx.x;
    int base = b * 1024;
    int v[4];
    int s = 0;
#pragma unroll
    for (int j = 0; j < 4; ++j) {
        int i = base + t * 4 + j;
        v[j] = (i < n) ? cnt[i] : 0;
        s += v[j];
    }
    int lane = t & 63, wid = t >> 6;
    int incl = s;
    for (int d = 1; d < 64; d <<= 1) {
        int w = __shfl_up(incl, d, 64);
        if (lane >= d) incl += w;
    }
    __shared__ int wsum[4];
    __shared__ int wbase[4];
    if (lane == 63) wsum[wid] = incl;
    __syncthreads();
    if (t == 0) {
        int r = 0;
        for (int i = 0; i < 4; ++i) { wbase[i] = r; r += wsum[i]; }
    }
    __syncthreads();
    int run = partials[b] + wbase[wid] + (incl - s);
#pragma unroll
    for (int j = 0; j < 4; ++j) {
        int i = base + t * 4 + j;
        if (i < n) {
            offsets[i] = run;
            run += v[j];
            if (i == n - 1) offsets[n] = run;
        }
    }
}

// Entry write via 64-bit atomicExch: device-scope atomic routes through the
// shared coherence point instead of dirtying the issuing XCD's private L2
// line -> csr stays cache-resident, kills the 105 MB full-line writeback
// storm (round-6 counter evidence: WRITE_SIZE = (E+N)*64B).
__global__ __launch_bounds__(256) void scatter_edges(
    const int* __restrict__ srcA, const int* __restrict__ dstA,
    const int* __restrict__ offsets, int* __restrict__ cursor,
    const float* __restrict__ a_src, const float* __restrict__ a_dst,
    unsigned long long* __restrict__ csr, int E)
{
    int i = blockIdx.x * blockDim.x + threadIdx.x;
    if (i >= E) return;
    int s = srcA[i], d = dstA[i];
    float e = a_src[s] + a_dst[d];
    e = fmaxf(e, NEG_SLOPE * e);
    float w = __expf(e);
    int pos = offsets[d] + atomicAdd(&cursor[d], 1);
    unsigned long long packed =
        (unsigned long long)(unsigned)s |
        ((unsigned long long)__float_as_uint(w) << 32);
    atomicExch(&csr[pos], packed);
}

// ---------------------------------------------------------------------------
// Kernel C: QUARTER-WAVE per node — 16 lanes/node, lane covers 4 bf16 cols
// (one 8B load per edge). Self-loop term computed analytically (no CSR
// entry). Trip-count divergence across the 4 groups is ~30% but wave-level
// instructions/edge drop and 4 independent gather streams hide latency.
// ---------------------------------------------------------------------------
__global__ __launch_bounds__(256) void gat_pull(
    const int* __restrict__ offsets, const int2* __restrict__ csr,
    const unsigned short* __restrict__ h, const float* __restrict__ a_src,
    const float* __restrict__ a_dst, const float* __restrict__ bias,
    float* __restrict__ out, int N)
{
    int gw   = (blockIdx.x * blockDim.x + threadIdx.x) >> 6;  // wave id
    int lane = threadIdx.x & 63;
    int grp  = lane >> 4;        // 0..3 : node within wave
    int gl   = lane & 15;        // lane within group; cols 4*gl..4*gl+3
    int node = gw * 4 + grp;
    bool valid = node < N;
    int nv = valid ? node : 0;

    int beg = offsets[nv];
    int n   = valid ? (offsets[nv + 1] - beg) : 0;   // may be 0 now
    const int2* ce = csr + (n ? beg : 0);

    // self-loop term (always present in reference softmax)
    float asv = a_src[nv], adv = a_dst[nv];
    float es = asv + adv; es = fmaxf(es, NEG_SLOPE * es);
    float ws = __expf(es);
    unsigned long long hu = *(const unsigned long long*)
        (h + (size_t)nv * C_OUT + 4 * gl);
    unsigned hl = (unsigned)hu, hh = (unsigned)(hu >> 32);
    float acc0 = ws * __uint_as_float(hl << 16);
    float acc1 = ws * __uint_as_float(hl & 0xffff0000u);
    float acc2 = ws * __uint_as_float(hh << 16);
    float acc3 = ws * __uint_as_float(hh & 0xffff0000u);
    float den = ws;

    // 2-deep pipelined edge loop
    int2 c0 = ce[0];
    int2 c1 = ce[(n > 1) ? 1 : 0];
    unsigned long long u0 = *(const unsigned long long*)
        (h + (size_t)c0.x * C_OUT + 4 * gl);
    unsigned long long u1 = *(const unsigned long long*)
        (h + (size_t)c1.x * C_OUT + 4 * gl);

    for (int p = 0; p < n; p += 2) {
        int2 m0 = ce[(p + 2 < n) ? p + 2 : 0];
        int2 m1 = ce[(p + 3 < n) ? p + 3 : 0];
        unsigned long long v0 = *(const unsigned long long*)
            (h + (size_t)m0.x * C_OUT + 4 * gl);
        unsigned long long v1 = *(const unsigned long long*)
            (h + (size_t)m1.x * C_OUT + 4 * gl);

        float w0 = __int_as_float(c0.y);
        float w1 = (p + 1 < n) ? __int_as_float(c1.y) : 0.f;
        unsigned l0 = (unsigned)u0, h0 = (unsigned)(u0 >> 32);
        unsigned l1 = (unsigned)u1, h1 = (unsigned)(u1 >> 32);
        den  += w0 + w1;
        acc0 += w0 * __uint_as_float(l0 << 16)
              + w1 * __uint_as_float(l1 << 16);
        acc1 += w0 * __uint_as_float(l0 & 0xffff0000u)
              + w1 * __uint_as_float(l1 & 0xffff0000u);
        acc2 += w0 * __uint_as_float(h0 << 16)
              + w1 * __uint_as_float(h1 << 16);
        acc3 += w0 * __uint_as_float(h0 & 0xffff0000u)
              + w1 * __uint_as_float(h1 & 0xffff0000u);

        c0 = m0; c1 = m1; u0 = v0; u1 = v1;
    }

    float4 bl = *(const float4*)(bias + 4 * gl);
    float rd = 1.f / den;
    float o0 = acc0 * rd + bl.x;
    float o1 = acc1 * rd + bl.y;
    float o2 = acc2 * rd + bl.z;
    float o3 = acc3 * rd + bl.w;

    // L2 norm within the 16-lane group (xor d=1..8 stays in-group)
    float sq = o0 * o0 + o1 * o1 + o2 * o2 + o3 * o3;
#pragma unroll
    for (int d = 1; d < 16; d <<= 1) sq += __shfl_xor(sq, d, 64);
    float rn = 1.f / fmaxf(sqrtf(sq), EPS_NRM);

    if (valid)
        *(float4*)(out + (size_t)node * C_OUT + 4 * gl) =
            make_float4(o0 * rn, o1 * rn, o2 * rn, o3 * rn);
}

// ---------------------------------------------------------------------------
extern "C" void kernel_launch(void* const* d_in, const int* in_sizes, int n_in,
                              void* d_out, int out_size, void* d_ws, size_t ws_size,
                              hipStream_t stream)
{
    const float* x     = (const float*)d_in[0];
    const int*   ei    = (const int*)d_in[1];   // [2][E], row0=src, row1=dst
    const float* W     = (const float*)d_in[2];
    const float* att_s = (const float*)d_in[3];
    const float* att_d = (const float*)d_in[4];
    const float* bias  = (const float*)d_in[5];
    float*       out   = (float*)d_out;

    const int OUT = in_sizes[3];          // 64
    const int IN  = in_sizes[2] / OUT;    // 256
    const int N   = in_sizes[0] / IN;     // 100000
    const int E   = in_sizes[1] / 2;      // 1600000

    // workspace carve-out (256B aligned) — ~27.6 MB total
    char* w = (char*)d_ws;
    auto alloc = [&](size_t bytes) -> void* {
        void* p = (void*)w;
        w += (bytes + 255) & ~(size_t)255;
        return p;
    };
    __hip_bfloat16* h = (__hip_bfloat16*)alloc((size_t)N * C_OUT * 2);
    float* a_src  = (float*)alloc((size_t)N * 4);
    float* a_dst  = (float*)alloc((size_t)N * 4);
    int*   cnt    = (int*)alloc((size_t)N * 2 * 4);  // [0..N) hist, [N..2N) cursor
    int*   offs   = (int*)alloc((size_t)(N + 1) * 4);
    int*   parts  = (int*)alloc(1024 * 4);
    unsigned long long* csr = (unsigned long long*)alloc((size_t)E * 8);
    int*   cursor = cnt + N;

    hipMemsetAsync(cnt, 0, (size_t)N * 2 * 4, stream);

    gemm_att<<<(N + ROWS_PB - 1) / ROWS_PB, 256, 0, stream>>>(
        x, W, att_s, att_d, h, a_src, a_dst, N);

    count_dst<<<(E + 255) / 256, 256, 0, stream>>>(ei + E, cnt, E);

    int NB = (N + 1023) / 1024;
    scan_p1<<<NB, 256, 0, stream>>>(cnt, parts, N);
    scan_p2<<<1, 256, 0, stream>>>(parts, NB);
    scan_p3<<<NB, 256, 0, stream>>>(cnt, parts, offs, N);

    scatter_edges<<<(E + 255) / 256, 256, 0, stream>>>(
        ei, ei + E, offs, cursor, a_src, a_dst, csr, E);

    // quarter-wave: 16 nodes per 256-thread block
    gat_pull<<<(N + 15) / 16, 256, 0, stream>>>(offs, (const int2*)csr,
        (const unsigned short*)h, a_src, a_dst, bias, out, N);
}

// Round 8
// 369.576 us; speedup vs baseline: 1.1725x; 1.1725x over previous
//
#include <hip/hip_runtime.h>
#include <hip/hip_bf16.h>
#include <math.h>

#define NEG_SLOPE 0.2f
#define EPS_NRM 1e-12f
#define K_IN 256
#define C_OUT 64
#define BK 32
#define ROWS_PB 128

// ---------------------------------------------------------------------------
// Kernel A: h = x @ W (+ fused a_src/a_dst scores), h stored as bf16.
// 2D register tile, x staged transposed, W staged [k][col].
// FUSED: dst-degree histogram (grid-stride) after the epilogue — counting is
// independent of the GEMM, so its atomic latency hides under other blocks'
// VALU work instead of costing a serial dispatch.
// ---------------------------------------------------------------------------
__global__ __launch_bounds__(256) void gemm_att(
    const float* __restrict__ x, const float* __restrict__ W,
    const float* __restrict__ att_s, const float* __restrict__ att_d,
    __hip_bfloat16* __restrict__ h, float* __restrict__ a_src_arr,
    float* __restrict__ a_dst_arr, int N,
    const int* __restrict__ dstA, int* __restrict__ cnt, int E)
{
    __shared__ float xt[BK][ROWS_PB];   // 16 KB, transposed
    __shared__ float wt[BK][C_OUT];     // 8 KB

    int t  = threadIdx.x;
    int tx = t & 15;
    int ty = t >> 4;
    int row0 = blockIdx.x * ROWS_PB;

    int sr  = t >> 1;
    int skh = (t & 1) * 16;
    int srow = row0 + sr; if (srow >= N) srow = N - 1;
    const float* xsp = x + (size_t)srow * K_IN + skh;

    float acc[8][4];
#pragma unroll
    for (int r = 0; r < 8; ++r)
#pragma unroll
        for (int c = 0; c < 4; ++c) acc[r][c] = 0.f;

    for (int k0 = 0; k0 < K_IN; k0 += BK) {
        float4 xa = *(const float4*)(xsp + k0);
        float4 xb = *(const float4*)(xsp + k0 + 4);
        float4 xc = *(const float4*)(xsp + k0 + 8);
        float4 xd = *(const float4*)(xsp + k0 + 12);
        float4 wv4a = *(const float4*)(W + (size_t)k0 * C_OUT + t * 4);
        float4 wv4b = *(const float4*)(W + (size_t)(k0 + 16) * C_OUT + t * 4);
        __syncthreads();
        xt[skh +  0][sr] = xa.x; xt[skh +  1][sr] = xa.y;
        xt[skh +  2][sr] = xa.z; xt[skh +  3][sr] = xa.w;
        xt[skh +  4][sr] = xb.x; xt[skh +  5][sr] = xb.y;
        xt[skh +  6][sr] = xb.z; xt[skh +  7][sr] = xb.w;
        xt[skh +  8][sr] = xc.x; xt[skh +  9][sr] = xc.y;
        xt[skh + 10][sr] = xc.z; xt[skh + 11][sr] = xc.w;
        xt[skh + 12][sr] = xd.x; xt[skh + 13][sr] = xd.y;
        xt[skh + 14][sr] = xd.z; xt[skh + 15][sr] = xd.w;
        *(float4*)(&wt[ 0][0] + t * 4) = wv4a;
        *(float4*)(&wt[16][0] + t * 4) = wv4b;
        __syncthreads();

#pragma unroll
        for (int k = 0; k < BK; ++k) {
            float xv[8];
            *(float4*)&xv[0] = *(const float4*)&xt[k][ty * 8];
            *(float4*)&xv[4] = *(const float4*)&xt[k][ty * 8 + 4];
            float4 wv = *(const float4*)&wt[k][tx * 4];
#pragma unroll
            for (int r = 0; r < 8; ++r) {
                acc[r][0] += xv[r] * wv.x;
                acc[r][1] += xv[r] * wv.y;
                acc[r][2] += xv[r] * wv.z;
                acc[r][3] += xv[r] * wv.w;
            }
        }
    }

    float4 avl = *(const float4*)(att_s + tx * 4);
    float4 dvl = *(const float4*)(att_d + tx * 4);
#pragma unroll
    for (int r = 0; r < 8; ++r) {
        int row = row0 + ty * 8 + r;
        if (row >= N) continue;
        float ps = acc[r][0] * avl.x + acc[r][1] * avl.y +
                   acc[r][2] * avl.z + acc[r][3] * avl.w;
        float pd = acc[r][0] * dvl.x + acc[r][1] * dvl.y +
                   acc[r][2] * dvl.z + acc[r][3] * dvl.w;
#pragma unroll
        for (int d = 1; d < 16; d <<= 1) {
            ps += __shfl_xor(ps, d, 64);
            pd += __shfl_xor(pd, d, 64);
        }
        if (tx == 0) { a_src_arr[row] = ps; a_dst_arr[row] = pd; }
        __hip_bfloat16 hb[4];
#pragma unroll
        for (int c = 0; c < 4; ++c) hb[c] = __float2bfloat16(acc[r][c]);
        *(ushort2*)(h + (size_t)row * C_OUT + tx * 4) =
            make_ushort2(*(unsigned short*)&hb[0], *(unsigned short*)&hb[1]);
        *(ushort2*)(h + (size_t)row * C_OUT + tx * 4 + 2) =
            make_ushort2(*(unsigned short*)&hb[2], *(unsigned short*)&hb[3]);
    }

    // ---- fused dst-degree histogram (independent of the GEMM above) ----
    int stride = gridDim.x * blockDim.x;
    for (int i = blockIdx.x * blockDim.x + t; i < E; i += stride)
        atomicAdd(&cnt[dstA[i]], 1);
}

// ---------------------------------------------------------------------------
// Scan over counts (self loops folded into gat_pull, no +1).
// ---------------------------------------------------------------------------
__global__ __launch_bounds__(256) void scan_p1(
    const int* __restrict__ cnt, int* __restrict__ partials, int n)
{
    int b = blockIdx.x, t = threadIdx.x;
    int base = b * 1024;
    int s = 0;
#pragma unroll
    for (int j = 0; j < 4; ++j) {
        int i = base + t * 4 + j;
        if (i < n) s += cnt[i];
    }
    for (int d = 1; d < 64; d <<= 1) s += __shfl_xor(s, d, 64);
    __shared__ int wsum[4];
    int lane = t & 63, wid = t >> 6;
    if (lane == 0) wsum[wid] = s;
    __syncthreads();
    if (t == 0) partials[b] = wsum[0] + wsum[1] + wsum[2] + wsum[3];
}

__global__ __launch_bounds__(256) void scan_p2(int* partials, int nb)
{
    __shared__ int buf[256];
    int t = threadIdx.x;
    int v = (t < nb) ? partials[t] : 0;
    buf[t] = v;
    __syncthreads();
    for (int d = 1; d < 256; d <<= 1) {
        int w = (t >= d) ? buf[t - d] : 0;
        __syncthreads();
        buf[t] += w;
        __syncthreads();
    }
    if (t < nb) partials[t] = buf[t] - v;  // exclusive
}

__global__ __launch_bounds__(256) void scan_p3(
    const int* __restrict__ cnt, const int* __restrict__ partials,
    int* __restrict__ offsets, int n)
{
    int b = blockIdx.x, t = threadIdx.x;
    int base = b * 1024;
    int v[4];
    int s = 0;
#pragma unroll
    for (int j = 0; j < 4; ++j) {
        int i = base + t * 4 + j;
        v[j] = (i < n) ? cnt[i] : 0;
        s += v[j];
    }
    int lane = t & 63, wid = t >> 6;
    int incl = s;
    for (int d = 1; d < 64; d <<= 1) {
        int w = __shfl_up(incl, d, 64);
        if (lane >= d) incl += w;
    }
    __shared__ int wsum[4];
    __shared__ int wbase[4];
    if (lane == 63) wsum[wid] = incl;
    __syncthreads();
    if (t == 0) {
        int r = 0;
        for (int i = 0; i < 4; ++i) { wbase[i] = r; r += wsum[i]; }
    }
    __syncthreads();
    int run = partials[b] + wbase[wid] + (incl - s);
#pragma unroll
    for (int j = 0; j < 4; ++j) {
        int i = base + t * 4 + j;
        if (i < n) {
            offsets[i] = run;
            run += v[j];
            if (i == n - 1) offsets[n] = run;
        }
    }
}

// Packed {src, w} entry via NONTEMPORAL store: skips write-allocate (no line
// fetch) and keeps random 8B stores out of L2 — attacks the E*64B partial-
// line writeback storm (round-6/7 counter evidence). atomicExch variant
// regressed (r7: 129us); plain store baseline is 85us.
__global__ __launch_bounds__(256) void scatter_edges(
    const int* __restrict__ srcA, const int* __restrict__ dstA,
    const int* __restrict__ offsets, int* __restrict__ cursor,
    const float* __restrict__ a_src, const float* __restrict__ a_dst,
    unsigned long long* __restrict__ csr, int E)
{
    int i = blockIdx.x * blockDim.x + threadIdx.x;
    if (i >= E) return;
    int s = srcA[i], d = dstA[i];
    float e = a_src[s] + a_dst[d];
    e = fmaxf(e, NEG_SLOPE * e);
    float w = __expf(e);
    int pos = offsets[d] + atomicAdd(&cursor[d], 1);
    unsigned long long packed =
        (unsigned long long)(unsigned)s |
        ((unsigned long long)__float_as_uint(w) << 32);
    __builtin_nontemporal_store(packed, &csr[pos]);
}

// ---------------------------------------------------------------------------
// Kernel C: QUARTER-WAVE per node — 16 lanes/node, lane covers 4 bf16 cols
// (one 8B load per edge). Self-loop term computed analytically.
// ---------------------------------------------------------------------------
__global__ __launch_bounds__(256) void gat_pull(
    const int* __restrict__ offsets, const int2* __restrict__ csr,
    const unsigned short* __restrict__ h, const float* __restrict__ a_src,
    const float* __restrict__ a_dst, const float* __restrict__ bias,
    float* __restrict__ out, int N)
{
    int gw   = (blockIdx.x * blockDim.x + threadIdx.x) >> 6;  // wave id
    int lane = threadIdx.x & 63;
    int grp  = lane >> 4;        // 0..3 : node within wave
    int gl   = lane & 15;        // lane within group; cols 4*gl..4*gl+3
    int node = gw * 4 + grp;
    bool valid = node < N;
    int nv = valid ? node : 0;

    int beg = offsets[nv];
    int n   = valid ? (offsets[nv + 1] - beg) : 0;   // may be 0
    const int2* ce = csr + (n ? beg : 0);

    // self-loop term (always present in reference softmax)
    float asv = a_src[nv], adv = a_dst[nv];
    float es = asv + adv; es = fmaxf(es, NEG_SLOPE * es);
    float ws = __expf(es);
    unsigned long long hu = *(const unsigned long long*)
        (h + (size_t)nv * C_OUT + 4 * gl);
    unsigned hl = (unsigned)hu, hh = (unsigned)(hu >> 32);
    float acc0 = ws * __uint_as_float(hl << 16);
    float acc1 = ws * __uint_as_float(hl & 0xffff0000u);
    float acc2 = ws * __uint_as_float(hh << 16);
    float acc3 = ws * __uint_as_float(hh & 0xffff0000u);
    float den = ws;

    // 2-deep pipelined edge loop
    int2 c0 = ce[0];
    int2 c1 = ce[(n > 1) ? 1 : 0];
    unsigned long long u0 = *(const unsigned long long*)
        (h + (size_t)c0.x * C_OUT + 4 * gl);
    unsigned long long u1 = *(const unsigned long long*)
        (h + (size_t)c1.x * C_OUT + 4 * gl);

    for (int p = 0; p < n; p += 2) {
        int2 m0 = ce[(p + 2 < n) ? p + 2 : 0];
        int2 m1 = ce[(p + 3 < n) ? p + 3 : 0];
        unsigned long long v0 = *(const unsigned long long*)
            (h + (size_t)m0.x * C_OUT + 4 * gl);
        unsigned long long v1 = *(const unsigned long long*)
            (h + (size_t)m1.x * C_OUT + 4 * gl);

        float w0 = __int_as_float(c0.y);
        float w1 = (p + 1 < n) ? __int_as_float(c1.y) : 0.f;
        unsigned l0 = (unsigned)u0, h0 = (unsigned)(u0 >> 32);
        unsigned l1 = (unsigned)u1, h1 = (unsigned)(u1 >> 32);
        den  += w0 + w1;
        acc0 += w0 * __uint_as_float(l0 << 16)
              + w1 * __uint_as_float(l1 << 16);
        acc1 += w0 * __uint_as_float(l0 & 0xffff0000u)
              + w1 * __uint_as_float(l1 & 0xffff0000u);
        acc2 += w0 * __uint_as_float(h0 << 16)
              + w1 * __uint_as_float(h1 << 16);
        acc3 += w0 * __uint_as_float(h0 & 0xffff0000u)
              + w1 * __uint_as_float(h1 & 0xffff0000u);

        c0 = m0; c1 = m1; u0 = v0; u1 = v1;
    }

    float4 bl = *(const float4*)(bias + 4 * gl);
    float rd = 1.f / den;
    float o0 = acc0 * rd + bl.x;
    float o1 = acc1 * rd + bl.y;
    float o2 = acc2 * rd + bl.z;
    float o3 = acc3 * rd + bl.w;

    // L2 norm within the 16-lane group (xor d=1..8 stays in-group)
    float sq = o0 * o0 + o1 * o1 + o2 * o2 + o3 * o3;
#pragma unroll
    for (int d = 1; d < 16; d <<= 1) sq += __shfl_xor(sq, d, 64);
    float rn = 1.f / fmaxf(sqrtf(sq), EPS_NRM);

    if (valid)
        *(float4*)(out + (size_t)node * C_OUT + 4 * gl) =
            make_float4(o0 * rn, o1 * rn, o2 * rn, o3 * rn);
}

// ---------------------------------------------------------------------------
extern "C" void kernel_launch(void* const* d_in, const int* in_sizes, int n_in,
                              void* d_out, int out_size, void* d_ws, size_t ws_size,
                              hipStream_t stream)
{
    const float* x     = (const float*)d_in[0];
    const int*   ei    = (const int*)d_in[1];   // [2][E], row0=src, row1=dst
    const float* W     = (const float*)d_in[2];
    const float* att_s = (const float*)d_in[3];
    const float* att_d = (const float*)d_in[4];
    const float* bias  = (const float*)d_in[5];
    float*       out   = (float*)d_out;

    const int OUT = in_sizes[3];          // 64
    const int IN  = in_sizes[2] / OUT;    // 256
    const int N   = in_sizes[0] / IN;     // 100000
    const int E   = in_sizes[1] / 2;      // 1600000

    // workspace carve-out (256B aligned) — ~27.6 MB total (r7-proven size)
    char* w = (char*)d_ws;
    auto alloc = [&](size_t bytes) -> void* {
        void* p = (void*)w;
        w += (bytes + 255) & ~(size_t)255;
        return p;
    };
    __hip_bfloat16* h = (__hip_bfloat16*)alloc((size_t)N * C_OUT * 2);
    float* a_src  = (float*)alloc((size_t)N * 4);
    float* a_dst  = (float*)alloc((size_t)N * 4);
    int*   cnt    = (int*)alloc((size_t)N * 2 * 4);  // [0..N) hist, [N..2N) cursor
    int*   offs   = (int*)alloc((size_t)(N + 1) * 4);
    int*   parts  = (int*)alloc(1024 * 4);
    unsigned long long* csr = (unsigned long long*)alloc((size_t)E * 8);
    int*   cursor = cnt + N;

    hipMemsetAsync(cnt, 0, (size_t)N * 2 * 4, stream);

    gemm_att<<<(N + ROWS_PB - 1) / ROWS_PB, 256, 0, stream>>>(
        x, W, att_s, att_d, h, a_src, a_dst, N, ei + E, cnt, E);

    int NB = (N + 1023) / 1024;
    scan_p1<<<NB, 256, 0, stream>>>(cnt, parts, N);
    scan_p2<<<1, 256, 0, stream>>>(parts, NB);
    scan_p3<<<NB, 256, 0, stream>>>(cnt, parts, offs, N);

    scatter_edges<<<(E + 255) / 256, 256, 0, stream>>>(
        ei, ei + E, offs, cursor, a_src, a_dst, csr, E);

    // quarter-wave: 16 nodes per 256-thread block
    gat_pull<<<(N + 15) / 16, 256, 0, stream>>>(offs, (const int2*)csr,
        (const unsigned short*)h, a_src, a_dst, bias, out, N);
}